// Round 1
// baseline (306.585 us; speedup 1.0000x reference)
//
#include <hip/hip_runtime.h>
#include <hip/hip_bf16.h>

typedef __attribute__((ext_vector_type(8))) short bf16x8;
typedef __attribute__((ext_vector_type(4))) float f32x4;
typedef __attribute__((ext_vector_type(4))) unsigned int u32x4;

#define NC 32
#define NO 32
#define HH 512
#define WWD 512
#define HW (HH * WWD)

#define TH 8
#define TW 64
#define HALO_H (TH + 2)   // 10
#define HALO_W (TW + 2)   // 66
#define NPIX (HALO_H * HALO_W)  // 660
#define NUNIT (NPIX * 4)        // 2640 (4 ic-groups of 8)
#define NITER 16                // 16 * TH = 128 rows per block

#define WS_STRIDE 289           // 288 floats per oc + 1 pad (bank spread)

__device__ __forceinline__ unsigned short f2bf(float f) {
    unsigned u = __builtin_bit_cast(unsigned, f);
    u += 0x7FFFu + ((u >> 16) & 1u);   // round-to-nearest-even
    return (unsigned short)(u >> 16);
}

__global__ __launch_bounds__(512, 2)
void conv3x3_mfma(const float* __restrict__ x,
                  const float* __restrict__ wk,
                  float* __restrict__ out) {
    // union LDS: weight staging (32*289*4 = 36992 B) then x tile (660*64 = 42240 B)
    __shared__ __align__(16) char smem[NPIX * 64];

    const int tid   = threadIdx.x;
    const int lane  = tid & 63;
    const int wv    = tid >> 6;       // wave 0..7 -> output row within tile
    const int col16 = lane & 15;
    const int g4    = lane >> 4;      // 0..3 (ic-group / D-row group)

    const int w0    = blockIdx.x * TW;          // 0..448
    const int hbase = blockIdx.y * (TH * NITER); // 0..384
    const int b     = blockIdx.z;

    // ---- stage weights -> LDS (padded), coalesced ----
    float* ws = (float*)smem;
    for (int i = tid; i < NO * 288; i += 512) {
        int oc = i / 288;
        ws[oc * WS_STRIDE + (i - oc * 288)] = wk[i];
    }
    __syncthreads();

    // ---- build B-fragments in registers: wf[tap][nfrag] ----
    // B[k=ic][col=oc]: lane holds ic = 8*g4 + j, oc = 16*n + col16
    bf16x8 wf[9][2];
    #pragma unroll
    for (int tap = 0; tap < 9; ++tap) {
        #pragma unroll
        for (int n = 0; n < 2; ++n) {
            bf16x8 f;
            #pragma unroll
            for (int j = 0; j < 8; ++j) {
                float v = ws[(n * 16 + col16) * WS_STRIDE + (g4 * 8 + j) * 9 + tap];
                f[j] = (short)f2bf(v);
            }
            wf[tap][n] = f;
        }
    }
    // barrier before x-tiles overwrite ws happens at loop head

    const float* xb = x + (size_t)b * NC * HW;
    float* ob = out + (size_t)b * NO * HW;

    float sv[6][8];  // staging registers: up to 6 units x 8 channels

    auto load_tile = [&](int h0) {
        #pragma unroll
        for (int k = 0; k < 6; ++k) {
            int u = tid + k * 512;
            if (u < NUNIT) {
                int g  = u / NPIX;          // ic-group 0..3
                int p  = u - g * NPIX;      // halo pixel 0..659
                int hh = p / HALO_W;
                int ww = p - hh * HALO_W;
                int row = h0 + hh - 1;
                int cl  = w0 + ww - 1;
                bool ok = ((unsigned)row < (unsigned)HH) && ((unsigned)cl < (unsigned)WWD);
                const float* src = xb + (g * 8) * HW + row * WWD + cl;
                #pragma unroll
                for (int j = 0; j < 8; ++j) {
                    float t = 0.f;
                    if (ok) t = src[j * HW];
                    sv[k][j] = t;
                }
            }
        }
    };

    load_tile(hbase);  // prefetch tile 0

    for (int it = 0; it < NITER; ++it) {
        const int h0 = hbase + it * TH;

        __syncthreads();  // previous compute done; LDS free (also fences wf build)

        // ---- write tile `it` regs -> LDS bf16 [pixel][ic], XOR-swizzled ----
        #pragma unroll
        for (int k = 0; k < 6; ++k) {
            int u = tid + k * 512;
            if (u < NUNIT) {
                int g = u / NPIX;
                int p = u - g * NPIX;
                unsigned q0 = (unsigned)f2bf(sv[k][0]) | ((unsigned)f2bf(sv[k][1]) << 16);
                unsigned q1 = (unsigned)f2bf(sv[k][2]) | ((unsigned)f2bf(sv[k][3]) << 16);
                unsigned q2 = (unsigned)f2bf(sv[k][4]) | ((unsigned)f2bf(sv[k][5]) << 16);
                unsigned q3 = (unsigned)f2bf(sv[k][6]) | ((unsigned)f2bf(sv[k][7]) << 16);
                int byte = (p * 64 + g * 16) ^ ((p & 7) << 4);
                u32x4 q = { q0, q1, q2, q3 };
                *(u32x4*)(smem + byte) = q;
            }
        }

        // ---- issue next tile's global loads (hide latency under compute) ----
        if (it + 1 < NITER) load_tile(h0 + TH);

        __syncthreads();  // tile `it` ready in LDS

        // ---- compute: wave wv owns output row h0+wv, 64 columns ----
        f32x4 acc[4][2];
        #pragma unroll
        for (int m = 0; m < 4; ++m) {
            #pragma unroll
            for (int n = 0; n < 2; ++n) {
                f32x4 z = {0.f, 0.f, 0.f, 0.f};
                acc[m][n] = z;
            }
        }

        #pragma unroll
        for (int dh = 0; dh < 3; ++dh) {
            #pragma unroll
            for (int dw = 0; dw < 3; ++dw) {
                const int tap = dh * 3 + dw;
                #pragma unroll
                for (int m = 0; m < 4; ++m) {
                    int p = (wv + dh) * HALO_W + m * 16 + col16 + dw;
                    int byte = (p * 64 + g4 * 16) ^ ((p & 7) << 4);
                    bf16x8 a = *(bf16x8*)(smem + byte);  // ds_read_b128, conflict-free
                    acc[m][0] = __builtin_amdgcn_mfma_f32_16x16x32_bf16(a, wf[tap][0], acc[m][0], 0, 0, 0);
                    acc[m][1] = __builtin_amdgcn_mfma_f32_16x16x32_bf16(a, wf[tap][1], acc[m][1], 0, 0, 0);
                }
            }
        }

        // ---- store: lane l, frag(m,n), reg r -> out[oc=16n+col16][h0+wv][w0+16m+4*g4+r]
        float* orow = ob + (h0 + wv) * WWD + w0;
        #pragma unroll
        for (int m = 0; m < 4; ++m) {
            #pragma unroll
            for (int n = 0; n < 2; ++n) {
                int oc = n * 16 + col16;
                int wc = m * 16 + g4 * 4;
                *(f32x4*)(orow + oc * HW + wc) = acc[m][n];
            }
        }
    }
}

extern "C" void kernel_launch(void* const* d_in, const int* in_sizes, int n_in,
                              void* d_out, int out_size, void* d_ws, size_t ws_size,
                              hipStream_t stream) {
    const float* x  = (const float*)d_in[0];
    const float* wk = (const float*)d_in[1];
    float* out = (float*)d_out;
    dim3 grid(WWD / TW, HH / (TH * NITER), 16);  // (8, 4, 16) = 512 blocks
    conv3x3_mfma<<<grid, 512, 0, stream>>>(x, wk, out);
}